// Round 11
// baseline (651.397 us; speedup 1.0000x reference)
//
#include <hip/hip_runtime.h>
#include <stdint.h>

// ---- Problem constants ----
#define NDRUGS 10000
#define NTAILS 20000
#define NE     1000000
#define SSIZE  16
#define SH     10240        // shard stride (ints) for deg shards
#define CSLOT  96           // candidate slots per drug
#define GRID   512          // 2 blocks/CU -- co-resident by construction

typedef unsigned int  u32;
typedef unsigned short u16;
typedef unsigned long long u64;
typedef __attribute__((ext_vector_type(8))) short bf16x8;
typedef __attribute__((ext_vector_type(4))) float f32x4;
#define U64MAX 0xffffffffffffffffULL

// ---- Threefry-2x32-20 (exact JAX semantics) ----
__host__ __device__ __forceinline__ void tf2x32(u32 k0, u32 k1, u32 x0, u32 x1,
                                                u32& o0, u32& o1) {
  u32 ks2 = k0 ^ k1 ^ 0x1BD11BDAu;
  x0 += k0; x1 += k1;
#define TFR(r) { x0 += x1; x1 = (x1 << r) | (x1 >> (32 - r)); x1 ^= x0; }
  TFR(13) TFR(15) TFR(26) TFR(6)
  x0 += k1; x1 += ks2 + 1u;
  TFR(17) TFR(29) TFR(16) TFR(24)
  x0 += ks2; x1 += k0 + 2u;
  TFR(13) TFR(15) TFR(26) TFR(6)
  x0 += k0; x1 += k1 + 3u;
  TFR(17) TFR(29) TFR(16) TFR(24)
  x0 += k1; x1 += ks2 + 4u;
  TFR(13) TFR(15) TFR(26) TFR(6)
  x0 += ks2; x1 += k0 + 5u;
#undef TFR
  o0 = x0; o1 = x1;
}

__device__ __forceinline__ u32 rbits32(u32 kx, u32 ky, u32 i) {
  u32 o0, o1;
  tf2x32(kx, ky, 0u, i, o0, o1);
  return o0 ^ o1;   // partitionable fold
}
#define SELKEY(e) ((((u64)(rbits32(k1x, k1y, (u32)(e)) >> 9)) << 32) | (u32)(e))
#define CSWAP(x, y) { u64 lo_ = x < y ? x : y; u64 hi_ = x < y ? y : x; x = lo_; y = hi_; }

// ---- bf16 helpers (RNE, matches np/jax bf16 cast) ----
__device__ __forceinline__ float q16(float f) {
  u32 x = __builtin_bit_cast(u32, f);
  u32 lsb = (x >> 16) & 1u;
  x = (x + 0x7fffu + lsb) & 0xffff0000u;
  return __builtin_bit_cast(float, x);
}
__device__ __forceinline__ u16 rne16(float f) {
  u32 x = __builtin_bit_cast(u32, f);
  u32 lsb = (x >> 16) & 1u;
  return (u16)((x + 0x7fffu + lsb) >> 16);
}
__device__ __forceinline__ float bfbits2f(u16 b) {
  u32 x = ((u32)b) << 16;
  return __builtin_bit_cast(float, x);
}

// ---- Software grid barrier (all GRID blocks co-resident) ----
// Release: __threadfence (agent scope -> L2 writeback across XCDs) + arrive.
// Acquire: agent-scope spin load + __threadfence (-> cache invalidate).
__device__ __forceinline__ void gbar(int* bar, int idx) {
  __syncthreads();
  if (threadIdx.x == 0) {
    __threadfence();
    __hip_atomic_fetch_add(&bar[idx], 1, __ATOMIC_RELEASE,
                           __HIP_MEMORY_SCOPE_AGENT);
    while (__hip_atomic_load(&bar[idx], __ATOMIC_ACQUIRE,
                             __HIP_MEMORY_SCOPE_AGENT) < GRID) {
      __builtin_amdgcn_s_sleep(2);
    }
    __threadfence();
  }
  __syncthreads();
}

struct MegaArgs {
  const int4*  dkg4;
  const int*   dkg;
  const float *drug, *rel, *tail, *W1, *b1, *W2, *b2, *Wc, *bc, *gamma, *beta;
  const float4 *HFE4, *Xv4;
  float4* out4;
  float*  y;        // d_out + 640000
  int*    bar;      // zeroed by host-side memset
  int*    degs;     // zeroed by host-side memset
  int*    cnt;
  u32*    thr;
  int*    deg;
  int*    sel;
  int*    cand;
  int*    flagl;
  int*    nflag;
  float*  psq;      // ps = psq[0..64), pq = psq[64..128)
  u32 k1x, k1y, khx, khy, klx, kly;
};

__global__ __launch_bounds__(256, 2) void k_mega(MegaArgs A) {
  __shared__ __align__(16) char smem[40960];
  // Per-phase LDS overlays (phases separated by gbar / __syncthreads):
  u32*   thr_l = (u32*)smem;                  // cand:   40000 B
  int*   asel  = (int*)smem;                  // select: [4][16] ints
  u64*   pool  = (u64*)smem;                  // fix:    32 KB
  float* nbuf  = (float*)smem;                // g+e:    [16][64] f32 (4 KB)
  float* rsp   = (float*)(smem + 4096);       // g:      [4][64] f32 (1 KB)
  u16*   Vh    = (u16*)(smem + 5120);         // g:      [4][16][72] (9 KB)
  u16*   Vl    = (u16*)(smem + 14336);        // g:      [4][16][72] (9 KB)
  u16*   Ah    = (u16*)(smem + 5120);         // e:      [16][136] (overlay Vh)
  u16*   Al    = (u16*)(smem + 9472);         // e:      [16][72]

  const int tid = threadIdx.x, lane = tid & 63, wv = tid >> 6;
  const int quad = lane >> 4, c = lane & 15;
  const int g = blockIdx.x * 256 + tid;
  const int T = GRID * 256;
  const u32 k1x = A.k1x, k1y = A.k1y;

  // ---- Phase 1: degree histogram (degs pre-zeroed by host memset) ----
  for (int i = g; i < NE / 4; i += T) {
    int4 a = A.dkg4[3 * i], b = A.dkg4[3 * i + 1], cc = A.dkg4[3 * i + 2];
    int s = (tid & 3) * SH;
    atomicAdd(&A.degs[s + a.x], 1);
    atomicAdd(&A.degs[s + a.w], 1);
    atomicAdd(&A.degs[s + b.z], 1);
    atomicAdd(&A.degs[s + cc.y], 1);
  }
  gbar(A.bar, 0);

  // ---- Phase 2: merge shards + threshold; zero cnt/psq/nflag ----
  for (int d = g; d < NDRUGS; d += T) {
    int dg = A.degs[d] + A.degs[SH + d] + A.degs[2 * SH + d] + A.degs[3 * SH + d];
    A.deg[d] = dg;
    A.cnt[d] = 0;
    A.thr[d] = (dg <= 40) ? 0x800000u
                          : (402653184u + (u32)dg - 1u) / (u32)dg;  // ceil(48*2^23/dg)
  }
  if (g < 128) A.psq[g] = 0.f;
  if (g == 0) *A.nflag = 0;
  gbar(A.bar, 1);

  // ---- Phase 3: candidate emission (thr staged in LDS) ----
  for (int j = tid; j < NDRUGS; j += 256) thr_l[j] = A.thr[j];
  __syncthreads();
  for (int i = g; i < NE / 4; i += T) {
    int4 a = A.dkg4[3 * i], b = A.dkg4[3 * i + 1], cc = A.dkg4[3 * i + 2];
    int h[4] = {a.x, a.w, b.z, cc.y};
    int e0 = 4 * i;
#pragma unroll
    for (int k = 0; k < 4; k++) {
      u32 rb = rbits32(k1x, k1y, (u32)(e0 + k));
      if ((rb >> 9) < thr_l[h[k]]) {
        int pos = atomicAdd(&A.cnt[h[k]], 1);
        if (pos < CSLOT) A.cand[h[k] * CSLOT + pos] = e0 + k;
        else if (pos == CSLOT) {
          int ix = atomicAdd(A.nflag, 1);
          if (ix < 256) A.flagl[ix] = h[k];
        }
      }
    }
  }
  gbar(A.bar, 2);

  // ---- Phase 4: wave-per-drug top-16 selection ----
  for (int d = blockIdx.x * 4 + wv; d < NDRUGS; d += GRID * 4) {
    int dg = A.deg[d], n = A.cnt[d], off = d * CSLOT;
    if (dg <= 0) {
      if (lane < 16) A.sel[d * SSIZE + lane] = -1;
      continue;
    }
    if (dg >= SSIZE) {
      if (n < SSIZE || n > CSLOT) {         // filter failed -> exact fallback
        if (lane == 0) {
          int ix = atomicAdd(A.nflag, 1);
          if (ix < 256) A.flagl[ix] = d;
        }
        continue;
      }
      u64 a0 = U64MAX, a1 = U64MAX;
      if (lane < n)      a0 = SELKEY(A.cand[off + lane]);
      if (lane + 64 < n) a1 = SELKEY(A.cand[off + lane + 64]);
      CSWAP(a0, a1)
      int h = 0; u32 my = 0;
#pragma unroll
      for (int r = 0; r < SSIZE; r++) {
        u64 ex = (h == 0) ? a0 : (h == 1) ? a1 : U64MAX;
        u64 gg = ex;
#pragma unroll
        for (int m = 1; m < 64; m <<= 1) {
          u64 o = __shfl_xor(gg, m, 64);
          gg = o < gg ? o : gg;
        }
        if (lane == r) my = (u32)gg;
        if (ex == gg) h++;
      }
      if (lane < 16) A.sel[d * SSIZE + lane] = (int)my;
    } else {
      // deg<16: thr passed all -> n == dg; ascending extraction + extras
      u64 a0 = (lane < n) ? SELKEY(A.cand[off + lane]) : U64MAX;
      int h = 0;
      for (int r = 0; r < n; r++) {
        u64 ex = (h == 0) ? a0 : U64MAX;
        u64 gg = ex;
#pragma unroll
        for (int m = 1; m < 64; m <<= 1) {
          u64 o = __shfl_xor(gg, m, 64);
          gg = o < gg ? o : gg;
        }
        if (lane == 0) asel[wv * 16 + r] = (int)(u32)gg;
        if (ex == gg) h++;
      }
      if (lane < n) A.sel[d * SSIZE + lane] = asel[wv * 16 + lane];
      int need = SSIZE - n;
      const u32 span = 0x7fffffffu;          // 2^31-1; 2^32 % span = 2
      if (lane < need) {
        u32 j = (u32)(d * SSIZE + lane);
        u32 hi = rbits32(A.khx, A.khy, j) % span;
        u32 lo = rbits32(A.klx, A.kly, j) % span;
        u32 u = (hi * 2u + lo) % span;       // uint32 wraparound: JAX-exact
        int idx = (int)(u % (u32)n);
        A.sel[d * SSIZE + n + lane] = asel[wv * 16 + idx];
      }
    }
  }
  gbar(A.bar, 3);

  // ---- Phase 5: exact fallback for flagged drugs (block 0; normally empty) ----
  if (blockIdx.x == 0) {
    int nf = *A.nflag;
    if (nf > 256) nf = 256;
    for (int f = 0; f < nf; f++) {
      int d = A.flagl[f];
      u64 loc[16];
#pragma unroll
      for (int i = 0; i < 16; i++) loc[i] = U64MAX;
      u64 mx = U64MAX; int mi = 0;
      for (int e = tid; e < NE; e += 256) {
        if (A.dkg[3 * e] == d) {
          u64 k = SELKEY(e);
          if (k < mx) {
            loc[mi] = k; mx = 0;
            for (int i = 0; i < 16; i++)
              if (loc[i] > mx) { mx = loc[i]; mi = i; }
          }
        }
      }
#pragma unroll
      for (int i = 0; i < 16; i++) pool[tid * 16 + i] = loc[i];
      __syncthreads();
      if (tid == 0) {
        u64 best[16];
#pragma unroll
        for (int i = 0; i < 16; i++) best[i] = U64MAX;
        u64 bm = U64MAX; int bi = 0;
        for (int i = 0; i < 256 * 16; i++) {
          u64 k = pool[i];
          if (k < bm) {
            best[bi] = k; bm = 0;
            for (int j = 0; j < 16; j++)
              if (best[j] > bm) { bm = best[j]; bi = j; }
          }
        }
        for (int s = 0; s < 16; s++) A.sel[d * SSIZE + s] = (int)(u32)best[s];
      }
      __syncthreads();
    }
  }
  gbar(A.bar, 4);

  // ---- Phase 6: fused gather (MFMA MLP + tail accumulate) + epi (concat GEMM)
  {
    int r_ = tid & 63, ks = tid >> 6;
    float s = 0.f;
    for (int k = ks * 16; k < ks * 16 + 16; k++) s += q16(A.W2[r_ * 64 + k]);
    rsp[ks * 64 + r_] = s;
  }
  __syncthreads();
  float b1t[4], w2t[4];
#pragma unroll
  for (int t = 0; t < 4; t++) {
    b1t[t] = q16(A.b1[t * 16 + c]);
    int rr = t * 16 + c;
    w2t[t] = rsp[rr] + rsp[64 + rr] + rsp[128 + rr] + rsp[192 + rr];
  }
  bf16x8 bw[4][2];
#pragma unroll
  for (int t = 0; t < 4; t++)
#pragma unroll
    for (int s = 0; s < 2; s++) {
      union { short h[8]; bf16x8 v; } u;
#pragma unroll
      for (int jj = 0; jj < 8; jj++)
        u.h[jj] = (short)rne16(A.W1[(s * 32 + quad * 8 + jj) * 64 + t * 16 + c]);
      bw[t][s] = u.v;
    }
  float sb2 = q16(A.b2[lane]);
#pragma unroll
  for (int m = 32; m; m >>= 1) sb2 += __shfl_xor(sb2, m, 64);
  bf16x8 bwc[4];                             // Wc frags for cols wv*16..+15
#pragma unroll
  for (int s = 0; s < 4; s++) {
    union { short h[8]; bf16x8 v; } u;
#pragma unroll
    for (int jj = 0; jj < 8; jj++)
      u.h[jj] = (short)rne16(A.Wc[(s * 32 + quad * 8 + jj) * 64 + wv * 16 + c]);
    bwc[s] = u.v;
  }
  float bct = q16(A.bc[wv * 16 + c]);

  for (int grp = blockIdx.x; grp < 625; grp += GRID) {
    __syncthreads();                         // protect nbuf/Ah reuse
    int d0 = grp * 16 + wv * 4;
    int sv = A.sel[d0 * SSIZE + lane];
    int es = sv < 0 ? 0 : sv;
    int rlv = A.dkg[3 * es + 2];
    int tlv = A.dkg[3 * es + 1];
#pragma unroll 1
    for (int dd = 0; dd < 4; dd++) {
      int d = d0 + dd;
      float dr = q16(A.drug[d * 64 + lane]);
#pragma unroll
      for (int e = 0; e < 16; e++) {
        int rl = __shfl(rlv, dd * 16 + e, 64);
        float v = dr * q16(A.rel[rl * 64 + lane]);
        u16 hb = rne16(v);
        float lo = v - bfbits2f(hb);
        Vh[(wv * 16 + e) * 72 + lane] = hb;
        Vl[(wv * 16 + e) * 72 + lane] = rne16(lo);     // exact split
      }
      bf16x8 ah[2], al[2];
#pragma unroll
      for (int s = 0; s < 2; s++) {
        ah[s] = *(const bf16x8*)&Vh[(wv * 16 + c) * 72 + s * 32 + quad * 8];
        al[s] = *(const bf16x8*)&Vl[(wv * 16 + c) * 72 + s * 32 + quad * 8];
      }
      f32x4 acc[4];
#pragma unroll
      for (int t = 0; t < 4; t++) {
        acc[t] = (f32x4){b1t[t], b1t[t], b1t[t], b1t[t]};
#pragma unroll
        for (int s = 0; s < 2; s++) {
          acc[t] = __builtin_amdgcn_mfma_f32_16x16x32_bf16(ah[s], bw[t][s], acc[t], 0, 0, 0);
          acc[t] = __builtin_amdgcn_mfma_f32_16x16x32_bf16(al[s], bw[t][s], acc[t], 0, 0, 0);
        }
      }
      float p[4] = {0.f, 0.f, 0.f, 0.f};
#pragma unroll
      for (int t = 0; t < 4; t++)
#pragma unroll
        for (int r = 0; r < 4; r++)
          p[r] = fmaf(1.f / (1.f + __expf(-acc[t][r])), w2t[t], p[r]);
#pragma unroll
      for (int m = 1; m < 16; m <<= 1) {
#pragma unroll
        for (int r = 0; r < 4; r++) p[r] += __shfl_xor(p[r], m, 64);
      }
#pragma unroll
      for (int r = 0; r < 4; r++) p[r] += sb2;
      float a0 = 0.f, a1 = 0.f, a2 = 0.f, a3 = 0.f;
#pragma unroll
      for (int e = 0; e < 16; e += 4) {
#pragma unroll
        for (int k = 0; k < 4; k++) {
          int sl = dd * 16 + e + k;
          int ee = __shfl(sv, sl, 64);
          int tl = __shfl(tlv, sl, 64);
          float sc = __shfl(p[(e + k) & 3], ((e + k) >> 2) << 4, 64);
          float tv = q16(A.tail[tl * 64 + lane]);
          if (ee >= 0) {
            if (k == 0) a0 = fmaf(sc, tv, a0);
            else if (k == 1) a1 = fmaf(sc, tv, a1);
            else if (k == 2) a2 = fmaf(sc, tv, a2);
            else a3 = fmaf(sc, tv, a3);
          }
        }
      }
      nbuf[(wv * 4 + dd) * 64 + lane] = (a0 + a1) + (a2 + a3);
    }
    __syncthreads();
    // Epi A-fragments: wave wv builds rows wv*4..+3 (lane = dim)
#pragma unroll
    for (int rr2 = 0; rr2 < 4; rr2++) {
      int row = wv * 4 + rr2;
      int d = grp * 16 + row;
      float dv = q16(A.drug[d * 64 + lane]);
      Ah[row * 136 + lane] = rne16(dv);
      float nv = nbuf[row * 64 + lane];
      u16 nh = rne16(nv);
      Ah[row * 136 + 64 + lane] = nh;
      Al[row * 72 + lane] = rne16(nv - bfbits2f(nh));
    }
    __syncthreads();
    f32x4 acc = (f32x4){bct, bct, bct, bct};
#pragma unroll
    for (int s = 0; s < 4; s++) {
      bf16x8 a = *(const bf16x8*)&Ah[c * 136 + s * 32 + quad * 8];
      acc = __builtin_amdgcn_mfma_f32_16x16x32_bf16(a, bwc[s], acc, 0, 0, 0);
    }
#pragma unroll
    for (int s = 0; s < 2; s++) {
      bf16x8 a = *(const bf16x8*)&Al[c * 72 + s * 32 + quad * 8];
      acc = __builtin_amdgcn_mfma_f32_16x16x32_bf16(a, bwc[2 + s], acc, 0, 0, 0);
    }
    float ssum = 0.f, qsum = 0.f;
#pragma unroll
    for (int r = 0; r < 4; r++) {
      int row = grp * 16 + quad * 4 + r;
      float v = acc[r];
      A.y[row * 64 + wv * 16 + c] = v;
      ssum += v;
      qsum = fmaf(v, v, qsum);
    }
    ssum += __shfl_xor(ssum, 16, 64); ssum += __shfl_xor(ssum, 32, 64);
    qsum += __shfl_xor(qsum, 16, 64); qsum += __shfl_xor(qsum, 32, 64);
    if (quad == 0) {
      atomicAdd(&A.psq[wv * 16 + c], ssum);
      atomicAdd(&A.psq[64 + wv * 16 + c], qsum);
    }
  }
  gbar(A.bar, 5);

  // ---- Phase 7: BN (in place) + passthrough copies ----
  for (int i4 = g; i4 < 322500; i4 += T) {
    if (i4 < 160000) {
      float4 a = A.HFE4[i4];
      a.x = q16(a.x); a.y = q16(a.y); a.z = q16(a.z); a.w = q16(a.w);
      A.out4[i4] = a;
    } else if (i4 < 320000) {
      int idx4 = i4 - 160000;
      int j0 = (idx4 * 4) & 63;
      float4 S = *(const float4*)&A.psq[j0];
      float4 Q = *(const float4*)&A.psq[64 + j0];
      float4 v = A.out4[i4];                 // y, in place
      float4 r;
#define BN1(X, SS, QQ, JJ)                                                  \
      { float m = SS / 10000.f;                                             \
        float inv = rsqrtf(QQ / 10000.f - m * m + 1e-5f);                   \
        r.X = q16(fmaf(q16(A.gamma[JJ]) * (v.X - m), inv, q16(A.beta[JJ]))); }
      BN1(x, S.x, Q.x, j0 + 0)
      BN1(y, S.y, Q.y, j0 + 1)
      BN1(z, S.z, Q.z, j0 + 2)
      BN1(w, S.w, Q.w, j0 + 3)
#undef BN1
      A.out4[i4] = r;
    } else {
      float4 a = A.Xv4[i4 - 320000];
      a.x = q16(a.x); a.y = q16(a.y); a.z = q16(a.z); a.w = q16(a.w);
      A.out4[i4] = a;
    }
  }
}

extern "C" void kernel_launch(void* const* d_in, const int* in_sizes, int n_in,
                              void* d_out, int out_size, void* d_ws, size_t ws_size,
                              hipStream_t stream) {
  char* w = (char*)d_ws;
  MegaArgs A;
  A.dkg4  = (const int4*)d_in[13];
  A.dkg   = (const int*)d_in[13];
  A.drug  = (const float*)d_in[2];
  A.rel   = (const float*)d_in[3];
  A.tail  = (const float*)d_in[4];
  A.W1    = (const float*)d_in[5];
  A.b1    = (const float*)d_in[6];
  A.W2    = (const float*)d_in[7];
  A.b2    = (const float*)d_in[8];
  A.Wc    = (const float*)d_in[9];
  A.bc    = (const float*)d_in[10];
  A.gamma = (const float*)d_in[11];
  A.beta  = (const float*)d_in[12];
  A.HFE4  = (const float4*)d_in[0];
  A.Xv4   = (const float4*)d_in[1];
  A.out4  = (float4*)d_out;
  A.y     = (float*)d_out + 640000;          // Output-1 region doubles as y

  // ---- Workspace layout (ws_size = 256 MiB, proven via R9 fill counters;
  //      no overlays needed) ----
  A.cand  = (int*)(w);                       // 3,840,000 B
  A.flagl = (int*)(w + 3900000);             // 1 KB
  A.bar   = (int*)(w + 4000000);             // 64 B   (zeroed by memset below)
  A.degs  = (int*)(w + 4000064);             // 163,840 B (zeroed by memset)
  A.sel   = (int*)(w + 4200000);             // 640,000 B
  A.cnt   = (int*)(w + 4900000);             // 40,000 B (zeroed in phase 2)
  A.thr   = (u32*)(w + 4940000);             // 40,000 B
  A.deg   = (int*)(w + 4980000);             // 40,000 B
  A.psq   = (float*)(w + 5020000);           // 512 B (zeroed in phase 2)
  A.nflag = (int*)(w + 5020512);             // 4 B  (zeroed in phase 2)

  // Threefry key derivation (seed 42, partitionable split semantics)
  u32 k2x, k2y;
  tf2x32(0u, 42u, 0u, 0u, A.k1x, A.k1y);     // split(key)[0] -> uniform r
  tf2x32(0u, 42u, 0u, 1u, k2x, k2y);         // split(key)[1] -> randint key
  tf2x32(k2x, k2y, 0u, 0u, A.khx, A.khy);    // split(k2)[0] -> higher_bits
  tf2x32(k2x, k2y, 0u, 1u, A.klx, A.kly);    // split(k2)[1] -> lower_bits

  hipMemsetAsync(w + 4000000, 0, 64 + 163840, stream);   // bar + degs
  k_mega<<<GRID, 256, 0, stream>>>(A);
}

// Round 12
// 479.922 us; speedup vs baseline: 1.3573x; 1.3573x over previous
//
#include <hip/hip_runtime.h>
#include <stdint.h>

// ---- Problem constants ----
#define NDRUGS 10000
#define NTAILS 20000
#define NE     1000000
#define SSIZE  16
#define SH     10240        // shard stride (ints) for deg shards
#define CSLOT  96           // candidate slots per drug
#define GRID   512          // 2 blocks/CU -- co-resident by construction

typedef unsigned int  u32;
typedef unsigned short u16;
typedef unsigned long long u64;
typedef __attribute__((ext_vector_type(8))) short bf16x8;
typedef __attribute__((ext_vector_type(4))) float f32x4;
#define U64MAX 0xffffffffffffffffULL

// ---- Threefry-2x32-20 (exact JAX semantics) ----
__host__ __device__ __forceinline__ void tf2x32(u32 k0, u32 k1, u32 x0, u32 x1,
                                                u32& o0, u32& o1) {
  u32 ks2 = k0 ^ k1 ^ 0x1BD11BDAu;
  x0 += k0; x1 += k1;
#define TFR(r) { x0 += x1; x1 = (x1 << r) | (x1 >> (32 - r)); x1 ^= x0; }
  TFR(13) TFR(15) TFR(26) TFR(6)
  x0 += k1; x1 += ks2 + 1u;
  TFR(17) TFR(29) TFR(16) TFR(24)
  x0 += ks2; x1 += k0 + 2u;
  TFR(13) TFR(15) TFR(26) TFR(6)
  x0 += k0; x1 += k1 + 3u;
  TFR(17) TFR(29) TFR(16) TFR(24)
  x0 += k1; x1 += ks2 + 4u;
  TFR(13) TFR(15) TFR(26) TFR(6)
  x0 += ks2; x1 += k0 + 5u;
#undef TFR
  o0 = x0; o1 = x1;
}

__device__ __forceinline__ u32 rbits32(u32 kx, u32 ky, u32 i) {
  u32 o0, o1;
  tf2x32(kx, ky, 0u, i, o0, o1);
  return o0 ^ o1;   // partitionable fold
}
#define SELKEY(e) ((((u64)(rbits32(k1x, k1y, (u32)(e)) >> 9)) << 32) | (u32)(e))
#define CSWAP(x, y) { u64 lo_ = x < y ? x : y; u64 hi_ = x < y ? y : x; x = lo_; y = hi_; }

// ---- bf16 helpers (RNE, matches np/jax bf16 cast) ----
__device__ __forceinline__ float q16(float f) {
  u32 x = __builtin_bit_cast(u32, f);
  u32 lsb = (x >> 16) & 1u;
  x = (x + 0x7fffu + lsb) & 0xffff0000u;
  return __builtin_bit_cast(float, x);
}
__device__ __forceinline__ u16 rne16(float f) {
  u32 x = __builtin_bit_cast(u32, f);
  u32 lsb = (x >> 16) & 1u;
  return (u16)((x + 0x7fffu + lsb) >> 16);
}
__device__ __forceinline__ float bfbits2f(u16 b) {
  u32 x = ((u32)b) << 16;
  return __builtin_bit_cast(float, x);
}

// ---- Software grid barrier (all GRID blocks co-resident) ----
// CRITICAL: spin with RELAXED loads (agent-scope relaxed load = coherent
// global_load sc0/sc1, NO buffer_inv). Acquire-invalidate exactly ONCE after
// the spin exits. R11's ACQUIRE-in-loop nuked the XCD L2 every iteration.
__device__ __forceinline__ void gbar(int* bar, int idx) {
  __syncthreads();
  if (threadIdx.x == 0) {
    __threadfence();                                   // release: wb dirty
    __hip_atomic_fetch_add(&bar[idx], 1, __ATOMIC_RELAXED,
                           __HIP_MEMORY_SCOPE_AGENT);
    while (__hip_atomic_load(&bar[idx], __ATOMIC_RELAXED,
                             __HIP_MEMORY_SCOPE_AGENT) < GRID) {
      __builtin_amdgcn_s_sleep(8);
    }
    __threadfence();                                   // acquire: inv once
  }
  __syncthreads();
}

struct MegaArgs {
  const int4*  dkg4;
  const int*   dkg;
  const float *drug, *rel, *tail, *W1, *b1, *W2, *b2, *Wc, *bc, *gamma, *beta;
  const float4 *HFE4, *Xv4;
  float4* out4;
  float*  y;        // d_out + 640000
  int*    bar;      // zeroed by host-side memset
  int*    degs;     // zeroed by host-side memset
  int*    cnt;
  int*    sel;
  int*    cand;
  int*    flagl;
  int*    nflag;
  float*  psq;      // ps = psq[0..64), pq = psq[64..128)
  u32 k1x, k1y, khx, khy, klx, kly;
};

__global__ __launch_bounds__(256, 2) void k_mega(MegaArgs A) {
  __shared__ __align__(16) char smem[40960];
  // Per-phase LDS overlays (phases separated by gbar / __syncthreads):
  u32*   thr_l = (u32*)smem;                  // cand:   40000 B
  int*   asel  = (int*)smem;                  // select: [4][16] ints
  u64*   pool  = (u64*)smem;                  // fix:    32 KB
  float* nbuf  = (float*)smem;                // g+e:    [16][64] f32 (4 KB)
  float* rsp   = (float*)(smem + 4096);       // g:      [4][64] f32 (1 KB)
  u16*   Vh    = (u16*)(smem + 5120);         // g:      [4][16][72] (9 KB)
  u16*   Vl    = (u16*)(smem + 14336);        // g:      [4][16][72] (9 KB)
  u16*   Ah    = (u16*)(smem + 5120);         // e:      [16][136] (overlay Vh)
  u16*   Al    = (u16*)(smem + 9472);         // e:      [16][72]

  const int tid = threadIdx.x, lane = tid & 63, wv = tid >> 6;
  const int quad = lane >> 4, c = lane & 15;
  const int g = blockIdx.x * 256 + tid;
  const int T = GRID * 256;
  const u32 k1x = A.k1x, k1y = A.k1y;

  // ---- Phase 1: histogram (degs pre-zeroed) + zero cnt/psq/nflag ----
  for (int d = g; d < NDRUGS; d += T) A.cnt[d] = 0;
  if (g < 128) A.psq[g] = 0.f;
  if (g == 0) *A.nflag = 0;
  for (int i = g; i < NE / 4; i += T) {
    int4 a = A.dkg4[3 * i], b = A.dkg4[3 * i + 1], cc = A.dkg4[3 * i + 2];
    int s = (tid & 3) * SH;
    atomicAdd(&A.degs[s + a.x], 1);
    atomicAdd(&A.degs[s + a.w], 1);
    atomicAdd(&A.degs[s + b.z], 1);
    atomicAdd(&A.degs[s + cc.y], 1);
  }
  gbar(A.bar, 0);

  // ---- Phase 2: candidate emission (thr computed into LDS per block) ----
  // thr: deg<=40 -> pass-all (exact, covers deg<16 extras); else ~48 mean.
  for (int j = tid; j < NDRUGS; j += 256) {
    int dg = A.degs[j] + A.degs[SH + j] + A.degs[2 * SH + j] + A.degs[3 * SH + j];
    thr_l[j] = (dg <= 40) ? 0x800000u
                          : (402653184u + (u32)dg - 1u) / (u32)dg;  // ceil(48*2^23/dg)
  }
  __syncthreads();
  for (int i = g; i < NE / 4; i += T) {
    int4 a = A.dkg4[3 * i], b = A.dkg4[3 * i + 1], cc = A.dkg4[3 * i + 2];
    int h[4] = {a.x, a.w, b.z, cc.y};
    int e0 = 4 * i;
#pragma unroll
    for (int k = 0; k < 4; k++) {
      u32 rb = rbits32(k1x, k1y, (u32)(e0 + k));
      if ((rb >> 9) < thr_l[h[k]]) {
        int pos = atomicAdd(&A.cnt[h[k]], 1);
        if (pos < CSLOT) A.cand[h[k] * CSLOT + pos] = e0 + k;
        else if (pos == CSLOT) {
          int ix = atomicAdd(A.nflag, 1);
          if (ix < 256) A.flagl[ix] = h[k];
        }
      }
    }
  }
  gbar(A.bar, 1);

  // ---- Phase 3: wave-per-drug top-16 selection ----
  for (int d = blockIdx.x * 4 + wv; d < NDRUGS; d += GRID * 4) {
    int dg = A.degs[d] + A.degs[SH + d] + A.degs[2 * SH + d] + A.degs[3 * SH + d];
    int n = A.cnt[d], off = d * CSLOT;
    if (dg <= 0) {
      if (lane < 16) A.sel[d * SSIZE + lane] = -1;
      continue;
    }
    if (dg >= SSIZE) {
      if (n < SSIZE || n > CSLOT) {         // filter failed -> exact fallback
        if (lane == 0) {
          int ix = atomicAdd(A.nflag, 1);
          if (ix < 256) A.flagl[ix] = d;
        }
        continue;
      }
      u64 a0 = U64MAX, a1 = U64MAX;
      if (lane < n)      a0 = SELKEY(A.cand[off + lane]);
      if (lane + 64 < n) a1 = SELKEY(A.cand[off + lane + 64]);
      CSWAP(a0, a1)
      int h = 0; u32 my = 0;
#pragma unroll
      for (int r = 0; r < SSIZE; r++) {
        u64 ex = (h == 0) ? a0 : (h == 1) ? a1 : U64MAX;
        u64 gg = ex;
#pragma unroll
        for (int m = 1; m < 64; m <<= 1) {
          u64 o = __shfl_xor(gg, m, 64);
          gg = o < gg ? o : gg;
        }
        if (lane == r) my = (u32)gg;
        if (ex == gg) h++;
      }
      if (lane < 16) A.sel[d * SSIZE + lane] = (int)my;
    } else {
      // deg<16: thr passed all -> n == dg; ascending extraction + extras
      u64 a0 = (lane < n) ? SELKEY(A.cand[off + lane]) : U64MAX;
      int h = 0;
      for (int r = 0; r < n; r++) {
        u64 ex = (h == 0) ? a0 : U64MAX;
        u64 gg = ex;
#pragma unroll
        for (int m = 1; m < 64; m <<= 1) {
          u64 o = __shfl_xor(gg, m, 64);
          gg = o < gg ? o : gg;
        }
        if (lane == 0) asel[wv * 16 + r] = (int)(u32)gg;
        if (ex == gg) h++;
      }
      if (lane < n) A.sel[d * SSIZE + lane] = asel[wv * 16 + lane];
      int need = SSIZE - n;
      const u32 span = 0x7fffffffu;          // 2^31-1; 2^32 % span = 2
      if (lane < need) {
        u32 j = (u32)(d * SSIZE + lane);
        u32 hi = rbits32(A.khx, A.khy, j) % span;
        u32 lo = rbits32(A.klx, A.kly, j) % span;
        u32 u = (hi * 2u + lo) % span;       // uint32 wraparound: JAX-exact
        int idx = (int)(u % (u32)n);
        A.sel[d * SSIZE + n + lane] = asel[wv * 16 + idx];
      }
    }
  }
  gbar(A.bar, 2);

  // ---- Phase 4: exact fallback for flagged drugs (block 0; normally empty) ----
  if (blockIdx.x == 0) {
    int nf = *A.nflag;
    if (nf > 256) nf = 256;
    for (int f = 0; f < nf; f++) {
      int d = A.flagl[f];
      u64 loc[16];
#pragma unroll
      for (int i = 0; i < 16; i++) loc[i] = U64MAX;
      u64 mx = U64MAX; int mi = 0;
      for (int e = tid; e < NE; e += 256) {
        if (A.dkg[3 * e] == d) {
          u64 k = SELKEY(e);
          if (k < mx) {
            loc[mi] = k; mx = 0;
            for (int i = 0; i < 16; i++)
              if (loc[i] > mx) { mx = loc[i]; mi = i; }
          }
        }
      }
#pragma unroll
      for (int i = 0; i < 16; i++) pool[tid * 16 + i] = loc[i];
      __syncthreads();
      if (tid == 0) {
        u64 best[16];
#pragma unroll
        for (int i = 0; i < 16; i++) best[i] = U64MAX;
        u64 bm = U64MAX; int bi = 0;
        for (int i = 0; i < 256 * 16; i++) {
          u64 k = pool[i];
          if (k < bm) {
            best[bi] = k; bm = 0;
            for (int j = 0; j < 16; j++)
              if (best[j] > bm) { bm = best[j]; bi = j; }
          }
        }
        for (int s = 0; s < 16; s++) A.sel[d * SSIZE + s] = (int)(u32)best[s];
      }
      __syncthreads();
    }
  }
  gbar(A.bar, 3);

  // ---- Phase 5: fused gather (MFMA MLP + tail accumulate) + epi (concat GEMM)
  {
    int r_ = tid & 63, ks = tid >> 6;
    float s = 0.f;
    for (int k = ks * 16; k < ks * 16 + 16; k++) s += q16(A.W2[r_ * 64 + k]);
    rsp[ks * 64 + r_] = s;
  }
  __syncthreads();
  float b1t[4], w2t[4];
#pragma unroll
  for (int t = 0; t < 4; t++) {
    b1t[t] = q16(A.b1[t * 16 + c]);
    int rr = t * 16 + c;
    w2t[t] = rsp[rr] + rsp[64 + rr] + rsp[128 + rr] + rsp[192 + rr];
  }
  bf16x8 bw[4][2];
#pragma unroll
  for (int t = 0; t < 4; t++)
#pragma unroll
    for (int s = 0; s < 2; s++) {
      union { short h[8]; bf16x8 v; } u;
#pragma unroll
      for (int jj = 0; jj < 8; jj++)
        u.h[jj] = (short)rne16(A.W1[(s * 32 + quad * 8 + jj) * 64 + t * 16 + c]);
      bw[t][s] = u.v;
    }
  float sb2 = q16(A.b2[lane]);
#pragma unroll
  for (int m = 32; m; m >>= 1) sb2 += __shfl_xor(sb2, m, 64);
  bf16x8 bwc[4];                             // Wc frags for cols wv*16..+15
#pragma unroll
  for (int s = 0; s < 4; s++) {
    union { short h[8]; bf16x8 v; } u;
#pragma unroll
    for (int jj = 0; jj < 8; jj++)
      u.h[jj] = (short)rne16(A.Wc[(s * 32 + quad * 8 + jj) * 64 + wv * 16 + c]);
    bwc[s] = u.v;
  }
  float bct = q16(A.bc[wv * 16 + c]);

  for (int grp = blockIdx.x; grp < 625; grp += GRID) {
    __syncthreads();                         // protect nbuf/Ah reuse
    int d0 = grp * 16 + wv * 4;
    int sv = A.sel[d0 * SSIZE + lane];
    int es = sv < 0 ? 0 : sv;
    int rlv = A.dkg[3 * es + 2];
    int tlv = A.dkg[3 * es + 1];
#pragma unroll 1
    for (int dd = 0; dd < 4; dd++) {
      int d = d0 + dd;
      float dr = q16(A.drug[d * 64 + lane]);
#pragma unroll
      for (int e = 0; e < 16; e++) {
        int rl = __shfl(rlv, dd * 16 + e, 64);
        float v = dr * q16(A.rel[rl * 64 + lane]);
        u16 hb = rne16(v);
        float lo = v - bfbits2f(hb);
        Vh[(wv * 16 + e) * 72 + lane] = hb;
        Vl[(wv * 16 + e) * 72 + lane] = rne16(lo);     // exact split
      }
      bf16x8 ah[2], al[2];
#pragma unroll
      for (int s = 0; s < 2; s++) {
        ah[s] = *(const bf16x8*)&Vh[(wv * 16 + c) * 72 + s * 32 + quad * 8];
        al[s] = *(const bf16x8*)&Vl[(wv * 16 + c) * 72 + s * 32 + quad * 8];
      }
      f32x4 acc[4];
#pragma unroll
      for (int t = 0; t < 4; t++) {
        acc[t] = (f32x4){b1t[t], b1t[t], b1t[t], b1t[t]};
#pragma unroll
        for (int s = 0; s < 2; s++) {
          acc[t] = __builtin_amdgcn_mfma_f32_16x16x32_bf16(ah[s], bw[t][s], acc[t], 0, 0, 0);
          acc[t] = __builtin_amdgcn_mfma_f32_16x16x32_bf16(al[s], bw[t][s], acc[t], 0, 0, 0);
        }
      }
      float p[4] = {0.f, 0.f, 0.f, 0.f};
#pragma unroll
      for (int t = 0; t < 4; t++)
#pragma unroll
        for (int r = 0; r < 4; r++)
          p[r] = fmaf(1.f / (1.f + __expf(-acc[t][r])), w2t[t], p[r]);
#pragma unroll
      for (int m = 1; m < 16; m <<= 1) {
#pragma unroll
        for (int r = 0; r < 4; r++) p[r] += __shfl_xor(p[r], m, 64);
      }
#pragma unroll
      for (int r = 0; r < 4; r++) p[r] += sb2;
      float a0 = 0.f, a1 = 0.f, a2 = 0.f, a3 = 0.f;
#pragma unroll
      for (int e = 0; e < 16; e += 4) {
#pragma unroll
        for (int k = 0; k < 4; k++) {
          int sl = dd * 16 + e + k;
          int ee = __shfl(sv, sl, 64);
          int tl = __shfl(tlv, sl, 64);
          float sc = __shfl(p[(e + k) & 3], ((e + k) >> 2) << 4, 64);
          float tv = q16(A.tail[tl * 64 + lane]);
          if (ee >= 0) {
            if (k == 0) a0 = fmaf(sc, tv, a0);
            else if (k == 1) a1 = fmaf(sc, tv, a1);
            else if (k == 2) a2 = fmaf(sc, tv, a2);
            else a3 = fmaf(sc, tv, a3);
          }
        }
      }
      nbuf[(wv * 4 + dd) * 64 + lane] = (a0 + a1) + (a2 + a3);
    }
    __syncthreads();
    // Epi A-fragments: wave wv builds rows wv*4..+3 (lane = dim)
#pragma unroll
    for (int rr2 = 0; rr2 < 4; rr2++) {
      int row = wv * 4 + rr2;
      int d = grp * 16 + row;
      float dv = q16(A.drug[d * 64 + lane]);
      Ah[row * 136 + lane] = rne16(dv);
      float nv = nbuf[row * 64 + lane];
      u16 nh = rne16(nv);
      Ah[row * 136 + 64 + lane] = nh;
      Al[row * 72 + lane] = rne16(nv - bfbits2f(nh));
    }
    __syncthreads();
    f32x4 acc = (f32x4){bct, bct, bct, bct};
#pragma unroll
    for (int s = 0; s < 4; s++) {
      bf16x8 a = *(const bf16x8*)&Ah[c * 136 + s * 32 + quad * 8];
      acc = __builtin_amdgcn_mfma_f32_16x16x32_bf16(a, bwc[s], acc, 0, 0, 0);
    }
#pragma unroll
    for (int s = 0; s < 2; s++) {
      bf16x8 a = *(const bf16x8*)&Al[c * 72 + s * 32 + quad * 8];
      acc = __builtin_amdgcn_mfma_f32_16x16x32_bf16(a, bwc[2 + s], acc, 0, 0, 0);
    }
    float ssum = 0.f, qsum = 0.f;
#pragma unroll
    for (int r = 0; r < 4; r++) {
      int row = grp * 16 + quad * 4 + r;
      float v = acc[r];
      A.y[row * 64 + wv * 16 + c] = v;
      ssum += v;
      qsum = fmaf(v, v, qsum);
    }
    ssum += __shfl_xor(ssum, 16, 64); ssum += __shfl_xor(ssum, 32, 64);
    qsum += __shfl_xor(qsum, 16, 64); qsum += __shfl_xor(qsum, 32, 64);
    if (quad == 0) {
      atomicAdd(&A.psq[wv * 16 + c], ssum);
      atomicAdd(&A.psq[64 + wv * 16 + c], qsum);
    }
  }
  gbar(A.bar, 4);

  // ---- Phase 6: BN (in place) + passthrough copies ----
  for (int i4 = g; i4 < 322500; i4 += T) {
    if (i4 < 160000) {
      float4 a = A.HFE4[i4];
      a.x = q16(a.x); a.y = q16(a.y); a.z = q16(a.z); a.w = q16(a.w);
      A.out4[i4] = a;
    } else if (i4 < 320000) {
      int idx4 = i4 - 160000;
      int j0 = (idx4 * 4) & 63;
      float4 S = *(const float4*)&A.psq[j0];
      float4 Q = *(const float4*)&A.psq[64 + j0];
      float4 v = A.out4[i4];                 // y, in place
      float4 r;
#define BN1(X, SS, QQ, JJ)                                                  \
      { float m = SS / 10000.f;                                             \
        float inv = rsqrtf(QQ / 10000.f - m * m + 1e-5f);                   \
        r.X = q16(fmaf(q16(A.gamma[JJ]) * (v.X - m), inv, q16(A.beta[JJ]))); }
      BN1(x, S.x, Q.x, j0 + 0)
      BN1(y, S.y, Q.y, j0 + 1)
      BN1(z, S.z, Q.z, j0 + 2)
      BN1(w, S.w, Q.w, j0 + 3)
#undef BN1
      A.out4[i4] = r;
    } else {
      float4 a = A.Xv4[i4 - 320000];
      a.x = q16(a.x); a.y = q16(a.y); a.z = q16(a.z); a.w = q16(a.w);
      A.out4[i4] = a;
    }
  }
}

extern "C" void kernel_launch(void* const* d_in, const int* in_sizes, int n_in,
                              void* d_out, int out_size, void* d_ws, size_t ws_size,
                              hipStream_t stream) {
  char* w = (char*)d_ws;
  MegaArgs A;
  A.dkg4  = (const int4*)d_in[13];
  A.dkg   = (const int*)d_in[13];
  A.drug  = (const float*)d_in[2];
  A.rel   = (const float*)d_in[3];
  A.tail  = (const float*)d_in[4];
  A.W1    = (const float*)d_in[5];
  A.b1    = (const float*)d_in[6];
  A.W2    = (const float*)d_in[7];
  A.b2    = (const float*)d_in[8];
  A.Wc    = (const float*)d_in[9];
  A.bc    = (const float*)d_in[10];
  A.gamma = (const float*)d_in[11];
  A.beta  = (const float*)d_in[12];
  A.HFE4  = (const float4*)d_in[0];
  A.Xv4   = (const float4*)d_in[1];
  A.out4  = (float4*)d_out;
  A.y     = (float*)d_out + 640000;          // Output-1 region doubles as y

  // ---- Workspace layout (ws_size = 256 MiB per R9 fill counters) ----
  A.cand  = (int*)(w);                       // 3,840,000 B
  A.flagl = (int*)(w + 3900000);             // 1 KB
  A.bar   = (int*)(w + 4000000);             // 64 B   (zeroed by memset below)
  A.degs  = (int*)(w + 4000064);             // 163,840 B (zeroed by memset)
  A.sel   = (int*)(w + 4200000);             // 640,000 B
  A.cnt   = (int*)(w + 4900000);             // 40,000 B (zeroed in phase 1)
  A.psq   = (float*)(w + 4940000);           // 512 B (zeroed in phase 1)
  A.nflag = (int*)(w + 4940512);             // 4 B  (zeroed in phase 1)

  // Threefry key derivation (seed 42, partitionable split semantics)
  u32 k2x, k2y;
  tf2x32(0u, 42u, 0u, 0u, A.k1x, A.k1y);     // split(key)[0] -> uniform r
  tf2x32(0u, 42u, 0u, 1u, k2x, k2y);         // split(key)[1] -> randint key
  tf2x32(k2x, k2y, 0u, 0u, A.khx, A.khy);    // split(k2)[0] -> higher_bits
  tf2x32(k2x, k2y, 0u, 1u, A.klx, A.kly);    // split(k2)[1] -> lower_bits

  hipMemsetAsync(w + 4000000, 0, 64 + 163840, stream);   // bar + degs
  k_mega<<<GRID, 256, 0, stream>>>(A);
}

// Round 13
// 274.809 us; speedup vs baseline: 2.3704x; 1.7464x over previous
//
#include <hip/hip_runtime.h>
#include <stdint.h>

// ---- Problem constants ----
#define NDRUGS 10000
#define NTAILS 20000
#define NE     1000000
#define SSIZE  16
#define SH     10240        // shard stride (ints) for deg shards
#define CSLOT  96           // candidate slots per drug

typedef unsigned int  u32;
typedef unsigned short u16;
typedef unsigned long long u64;
typedef __attribute__((ext_vector_type(8))) short bf16x8;
typedef __attribute__((ext_vector_type(4))) float f32x4;
#define U64MAX 0xffffffffffffffffULL

// ---- Threefry-2x32-20 (exact JAX semantics) ----
__host__ __device__ __forceinline__ void tf2x32(u32 k0, u32 k1, u32 x0, u32 x1,
                                                u32& o0, u32& o1) {
  u32 ks2 = k0 ^ k1 ^ 0x1BD11BDAu;
  x0 += k0; x1 += k1;
#define TFR(r) { x0 += x1; x1 = (x1 << r) | (x1 >> (32 - r)); x1 ^= x0; }
  TFR(13) TFR(15) TFR(26) TFR(6)
  x0 += k1; x1 += ks2 + 1u;
  TFR(17) TFR(29) TFR(16) TFR(24)
  x0 += ks2; x1 += k0 + 2u;
  TFR(13) TFR(15) TFR(26) TFR(6)
  x0 += k0; x1 += k1 + 3u;
  TFR(17) TFR(29) TFR(16) TFR(24)
  x0 += k1; x1 += ks2 + 4u;
  TFR(13) TFR(15) TFR(26) TFR(6)
  x0 += ks2; x1 += k0 + 5u;
#undef TFR
  o0 = x0; o1 = x1;
}

__device__ __forceinline__ u32 rbits32(u32 kx, u32 ky, u32 i) {
  u32 o0, o1;
  tf2x32(kx, ky, 0u, i, o0, o1);
  return o0 ^ o1;   // partitionable fold
}
#define SELKEY(e) ((((u64)(rbits32(k1x, k1y, (u32)(e)) >> 9)) << 32) | (u32)(e))
#define CSWAP(x, y) { u64 lo_ = x < y ? x : y; u64 hi_ = x < y ? y : x; x = lo_; y = hi_; }

// ---- bf16 helpers (RNE, matches np/jax bf16 cast) ----
__device__ __forceinline__ float q16(float f) {
  u32 x = __builtin_bit_cast(u32, f);
  u32 lsb = (x >> 16) & 1u;
  x = (x + 0x7fffu + lsb) & 0xffff0000u;
  return __builtin_bit_cast(float, x);
}
__device__ __forceinline__ u16 rne16(float f) {
  u32 x = __builtin_bit_cast(u32, f);
  u32 lsb = (x >> 16) & 1u;
  return (u16)((x + 0x7fffu + lsb) >> 16);
}
__device__ __forceinline__ float bfbits2f(u16 b) {
  u32 x = ((u32)b) << 16;
  return __builtin_bit_cast(float, x);
}

// ---- Phase 1: degree histogram (sharded) + zero cnt ----
__global__ __launch_bounds__(256) void k_hist(const int4* __restrict__ dkg4,
                                              int* __restrict__ degs,
                                              int* __restrict__ cnt) {
  int i = blockIdx.x * 256 + threadIdx.x;
  if (i < NDRUGS) cnt[i] = 0;
  if (i >= NE / 4) return;
  int4 A = dkg4[3 * i], B = dkg4[3 * i + 1], C = dkg4[3 * i + 2];
  int s = (threadIdx.x & 3) * SH;
  atomicAdd(&degs[s + A.x], 1);
  atomicAdd(&degs[s + A.w], 1);
  atomicAdd(&degs[s + B.z], 1);
  atomicAdd(&degs[s + C.y], 1);
}

// ---- Phase 2: candidate emission; thr computed into LDS per block ----
// thr: deg<=40 -> pass-all (exact, covers deg<16 extras); else mean ~48.
__global__ __launch_bounds__(256) void k_cand(const int4* __restrict__ dkg4,
                                              const int* __restrict__ degs,
                                              int* __restrict__ cnt,
                                              int* __restrict__ cand,
                                              float* __restrict__ psq,
                                              u32 k1x, u32 k1y) {
  __shared__ u32 thr_l[NDRUGS];               // 40 KB
  int g = blockIdx.x * 256 + threadIdx.x;
  if (g < 128) psq[g] = 0.f;
  for (int j = threadIdx.x; j < NDRUGS; j += 256) {
    int dg = degs[j] + degs[SH + j] + degs[2 * SH + j] + degs[3 * SH + j];
    thr_l[j] = (dg <= 40) ? 0x800000u
                          : (402653184u + (u32)dg - 1u) / (u32)dg;  // ceil(48*2^23/dg)
  }
  __syncthreads();
  if (g >= NE / 4) return;
  int4 A = dkg4[3 * g], B = dkg4[3 * g + 1], C = dkg4[3 * g + 2];
  int h[4] = {A.x, A.w, B.z, C.y};
  int e0 = 4 * g;
#pragma unroll
  for (int k = 0; k < 4; k++) {
    u32 rb = rbits32(k1x, k1y, (u32)(e0 + k));
    if ((rb >> 9) < thr_l[h[k]]) {
      int pos = atomicAdd(&cnt[h[k]], 1);
      if (pos < CSLOT) cand[h[k] * CSLOT + pos] = e0 + k;
      // overflow (pos >= CSLOT): detected in k_ge via cnt > CSLOT -> fallback
    }
  }
}

// ---- Phase 3: fused select (in-register) + gather (MFMA MLP) + epi ----
// 625 blocks x 4 waves; block owns 16 drugs (wave wv: drugs blk*16+wv*4..+3).
// Select: per wave, exact top-16 per drug from cand (ascending); extras for
// deg<16; full-scan fallback if the candidate filter failed (P ~ 1e-10).
__global__ __launch_bounds__(256, 2) void k_ge(const int* __restrict__ dkg,
                                               const int* __restrict__ cand,
                                               const int* __restrict__ cnt,
                                               const int* __restrict__ degs,
                                               const float* __restrict__ drug,
                                               const float* __restrict__ rel,
                                               const float* __restrict__ tail,
                                               const float* __restrict__ W1,
                                               const float* __restrict__ b1,
                                               const float* __restrict__ W2,
                                               const float* __restrict__ b2,
                                               const float* __restrict__ Wc,
                                               const float* __restrict__ bc,
                                               float* __restrict__ y,
                                               float* __restrict__ psq,
                                               u32 k1x, u32 k1y,
                                               u32 khx, u32 khy,
                                               u32 klx, u32 kly) {
  __shared__ __align__(16) float nbuf[16][64];     // 4 KB
  __shared__ float rsp[4][64];                     // 1 KB
  __shared__ __align__(16) u16 Vh[4][16][72];      // 9 KB
  __shared__ __align__(16) u16 Vl[4][16][72];      // 9 KB
  __shared__ __align__(16) u16 Ah[16][136];        // 4.25 KB
  __shared__ __align__(16) u16 Al[16][72];         // 2.25 KB
  int tid = threadIdx.x, lane = tid & 63, wv = tid >> 6;
  int quad = lane >> 4, c = lane & 15;

  // ---- Weight staging (once per block/wave) ----
  {
    int r_ = tid & 63, ks = tid >> 6;
    float s = 0.f;
    for (int k = ks * 16; k < ks * 16 + 16; k++) s += q16(W2[r_ * 64 + k]);
    rsp[ks][r_] = s;
  }
  __syncthreads();
  float b1t[4], w2t[4];
#pragma unroll
  for (int t = 0; t < 4; t++) {
    b1t[t] = q16(b1[t * 16 + c]);
    int rr = t * 16 + c;
    w2t[t] = rsp[0][rr] + rsp[1][rr] + rsp[2][rr] + rsp[3][rr];
  }
  bf16x8 bw[4][2];
#pragma unroll
  for (int t = 0; t < 4; t++)
#pragma unroll
    for (int s = 0; s < 2; s++) {
      union { short h[8]; bf16x8 v; } u;
#pragma unroll
      for (int jj = 0; jj < 8; jj++)
        u.h[jj] = (short)rne16(W1[(s * 32 + quad * 8 + jj) * 64 + t * 16 + c]);
      bw[t][s] = u.v;
    }
  float sb2 = q16(b2[lane]);
#pragma unroll
  for (int m = 32; m; m >>= 1) sb2 += __shfl_xor(sb2, m, 64);
  bf16x8 bwc[4];                             // Wc frags for cols wv*16..+15
#pragma unroll
  for (int s = 0; s < 4; s++) {
    union { short h[8]; bf16x8 v; } u;
#pragma unroll
    for (int jj = 0; jj < 8; jj++)
      u.h[jj] = (short)rne16(Wc[(s * 32 + quad * 8 + jj) * 64 + wv * 16 + c]);
    bwc[s] = u.v;
  }
  float bct = q16(bc[wv * 16 + c]);

  // ---- In-register selection for this wave's 4 drugs ----
  int d0 = blockIdx.x * 16 + wv * 4;
  int sv = -1;
#pragma unroll 1
  for (int dd = 0; dd < 4; dd++) {
    int d = d0 + dd;
    int dg = degs[d] + degs[SH + d] + degs[2 * SH + d] + degs[3 * SH + d];
    int n = cnt[d], off = d * CSLOT;
    u32 my = 0xffffffffu;                    // invalid marker
    if (dg > 0) {
      if (dg >= SSIZE && (n >= SSIZE && n <= CSLOT)) {
        // normal: exact top-16 of candidate keys (ascending into lanes 0-15)
        u64 a0 = U64MAX, a1 = U64MAX;
        if (lane < n)      a0 = SELKEY(cand[off + lane]);
        if (lane + 64 < n) a1 = SELKEY(cand[off + lane + 64]);
        CSWAP(a0, a1)
        int h = 0;
#pragma unroll
        for (int r = 0; r < SSIZE; r++) {
          u64 ex = (h == 0) ? a0 : (h == 1) ? a1 : U64MAX;
          u64 gg = ex;
#pragma unroll
          for (int m = 1; m < 64; m <<= 1) {
            u64 o = __shfl_xor(gg, m, 64);
            gg = o < gg ? o : gg;
          }
          if (lane == r) my = (u32)gg;
          if (ex == gg) h++;
        }
      } else if (dg >= SSIZE) {
        // filter failed (~never): exact full-scan fallback
        u64 loc[16];
#pragma unroll
        for (int i = 0; i < 16; i++) loc[i] = U64MAX;
        u64 mx = U64MAX; int mi = 0;
        for (int e = lane; e < NE; e += 64) {
          if (dkg[3 * e] == d) {
            u64 k = SELKEY(e);
            if (k < mx) {
              loc[mi] = k; mx = 0;
              for (int i = 0; i < 16; i++)
                if (loc[i] > mx) { mx = loc[i]; mi = i; }
            }
          }
        }
        for (int r = 0; r < SSIZE; r++) {
          u64 ex = U64MAX; int xi = 0;
          for (int i = 0; i < 16; i++)
            if (loc[i] < ex) { ex = loc[i]; xi = i; }
          u64 gg = ex;
#pragma unroll
          for (int m = 1; m < 64; m <<= 1) {
            u64 o = __shfl_xor(gg, m, 64);
            gg = o < gg ? o : gg;
          }
          if (lane == r) my = (u32)gg;
          if (ex == gg) loc[xi] = U64MAX;    // keys unique: one lane
        }
      } else {
        // dg<16: thr passed all -> n == dg; ascending + extras
        u64 a0 = (lane < n) ? SELKEY(cand[off + lane]) : U64MAX;
        int h = 0;
        for (int r = 0; r < n; r++) {
          u64 ex = (h == 0) ? a0 : U64MAX;
          u64 gg = ex;
#pragma unroll
          for (int m = 1; m < 64; m <<= 1) {
            u64 o = __shfl_xor(gg, m, 64);
            gg = o < gg ? o : gg;
          }
          if (lane == r) my = (u32)gg;
          if (ex == gg) h++;
        }
        int src = lane;
        if (lane >= n && lane < SSIZE) {
          const u32 span = 0x7fffffffu;      // 2^31-1; 2^32 % span = 2
          u32 j = (u32)(d * SSIZE + (lane - n));
          u32 hi = rbits32(khx, khy, j) % span;
          u32 lo = rbits32(klx, kly, j) % span;
          u32 u = (hi * 2u + lo) % span;     // uint32 wraparound: JAX-exact
          src = (int)(u % (u32)n);
        }
        my = __shfl(my, src, 64);
      }
    }
    u32 got = __shfl(my, lane & 15, 64);
    if ((lane >> 4) == dd) sv = (got == 0xffffffffu) ? -1 : (int)got;
  }
  int es = sv < 0 ? 0 : sv;
  int rlv = dkg[3 * es + 2];
  int tlv = dkg[3 * es + 1];

  // ---- Gather: MFMA edge-MLP + tail accumulate (4 drugs/wave) ----
#pragma unroll 1
  for (int dd = 0; dd < 4; dd++) {
    int d = d0 + dd;
    float dr = q16(drug[d * 64 + lane]);
#pragma unroll
    for (int e = 0; e < 16; e++) {
      int rl = __shfl(rlv, dd * 16 + e, 64);
      float v = dr * q16(rel[rl * 64 + lane]);
      u16 hb = rne16(v);
      float lo = v - bfbits2f(hb);
      Vh[wv][e][lane] = hb;
      Vl[wv][e][lane] = rne16(lo);          // exact split
    }
    bf16x8 ah[2], al[2];
#pragma unroll
    for (int s = 0; s < 2; s++) {
      ah[s] = *(const bf16x8*)&Vh[wv][c][s * 32 + quad * 8];
      al[s] = *(const bf16x8*)&Vl[wv][c][s * 32 + quad * 8];
    }
    f32x4 acc[4];
#pragma unroll
    for (int t = 0; t < 4; t++) {
      acc[t] = (f32x4){b1t[t], b1t[t], b1t[t], b1t[t]};
#pragma unroll
      for (int s = 0; s < 2; s++) {
        acc[t] = __builtin_amdgcn_mfma_f32_16x16x32_bf16(ah[s], bw[t][s], acc[t], 0, 0, 0);
        acc[t] = __builtin_amdgcn_mfma_f32_16x16x32_bf16(al[s], bw[t][s], acc[t], 0, 0, 0);
      }
    }
    float p[4] = {0.f, 0.f, 0.f, 0.f};
#pragma unroll
    for (int t = 0; t < 4; t++)
#pragma unroll
      for (int r = 0; r < 4; r++)
        p[r] = fmaf(1.f / (1.f + __expf(-acc[t][r])), w2t[t], p[r]);
#pragma unroll
    for (int m = 1; m < 16; m <<= 1) {
#pragma unroll
      for (int r = 0; r < 4; r++) p[r] += __shfl_xor(p[r], m, 64);
    }
#pragma unroll
    for (int r = 0; r < 4; r++) p[r] += sb2;
    float a0 = 0.f, a1 = 0.f, a2 = 0.f, a3 = 0.f;
#pragma unroll
    for (int e = 0; e < 16; e += 4) {
#pragma unroll
      for (int k = 0; k < 4; k++) {
        int sl = dd * 16 + e + k;
        int ee = __shfl(sv, sl, 64);
        int tl = __shfl(tlv, sl, 64);
        float sc = __shfl(p[(e + k) & 3], ((e + k) >> 2) << 4, 64);
        float tv = q16(tail[tl * 64 + lane]);
        if (ee >= 0) {
          if (k == 0) a0 = fmaf(sc, tv, a0);
          else if (k == 1) a1 = fmaf(sc, tv, a1);
          else if (k == 2) a2 = fmaf(sc, tv, a2);
          else a3 = fmaf(sc, tv, a3);
        }
      }
    }
    nbuf[wv * 4 + dd][lane] = (a0 + a1) + (a2 + a3);
  }
  __syncthreads();

  // ---- Epi: y = [drug | neigh] @ Wc + bc via MFMA + stats ----
#pragma unroll
  for (int rr2 = 0; rr2 < 4; rr2++) {
    int row = wv * 4 + rr2;
    int d = blockIdx.x * 16 + row;
    float dv = q16(drug[d * 64 + lane]);
    Ah[row][lane] = rne16(dv);
    float nv = nbuf[row][lane];
    u16 nh = rne16(nv);
    Ah[row][64 + lane] = nh;
    Al[row][lane] = rne16(nv - bfbits2f(nh));
  }
  __syncthreads();
  f32x4 acc = (f32x4){bct, bct, bct, bct};
#pragma unroll
  for (int s = 0; s < 4; s++) {
    bf16x8 a = *(const bf16x8*)&Ah[c][s * 32 + quad * 8];
    acc = __builtin_amdgcn_mfma_f32_16x16x32_bf16(a, bwc[s], acc, 0, 0, 0);
  }
#pragma unroll
  for (int s = 0; s < 2; s++) {
    bf16x8 a = *(const bf16x8*)&Al[c][s * 32 + quad * 8];
    acc = __builtin_amdgcn_mfma_f32_16x16x32_bf16(a, bwc[2 + s], acc, 0, 0, 0);
  }
  float ssum = 0.f, qsum = 0.f;
#pragma unroll
  for (int r = 0; r < 4; r++) {
    int row = blockIdx.x * 16 + quad * 4 + r;
    float v = acc[r];
    y[row * 64 + wv * 16 + c] = v;
    ssum += v;
    qsum = fmaf(v, v, qsum);
  }
  ssum += __shfl_xor(ssum, 16, 64); ssum += __shfl_xor(ssum, 32, 64);
  qsum += __shfl_xor(qsum, 16, 64); qsum += __shfl_xor(qsum, 32, 64);
  if (quad == 0) {
    atomicAdd(&psq[wv * 16 + c], ssum);
    atomicAdd(&psq[64 + wv * 16 + c], qsum);
  }
}

// ---- Phase 4: BN (in place) + passthrough copies, float4 ----
__global__ __launch_bounds__(256) void k_final(const float4* __restrict__ HFE4,
                                               const float4* __restrict__ Xv4,
                                               const float* __restrict__ gamma,
                                               const float* __restrict__ beta,
                                               const float* __restrict__ psq,
                                               float4* __restrict__ out4) {
  int i4 = blockIdx.x * 256 + threadIdx.x;
  if (i4 < 160000) {
    float4 a = HFE4[i4];
    a.x = q16(a.x); a.y = q16(a.y); a.z = q16(a.z); a.w = q16(a.w);
    out4[i4] = a;
  } else if (i4 < 320000) {
    int idx4 = i4 - 160000;
    int j0 = (idx4 * 4) & 63;
    float4 S = *(const float4*)&psq[j0];
    float4 Q = *(const float4*)&psq[64 + j0];
    float4 v = out4[i4];                      // y, in place
    float4 r;
#define BN1(X, SS, QQ, JJ)                                                 \
    { float m = SS / 10000.f;                                              \
      float inv = rsqrtf(QQ / 10000.f - m * m + 1e-5f);                    \
      r.X = q16(fmaf(q16(gamma[JJ]) * (v.X - m), inv, q16(beta[JJ]))); }
    BN1(x, S.x, Q.x, j0 + 0)
    BN1(y, S.y, Q.y, j0 + 1)
    BN1(z, S.z, Q.z, j0 + 2)
    BN1(w, S.w, Q.w, j0 + 3)
#undef BN1
    out4[i4] = r;
  } else if (i4 < 322500) {
    float4 a = Xv4[i4 - 320000];
    a.x = q16(a.x); a.y = q16(a.y); a.z = q16(a.z); a.w = q16(a.w);
    out4[i4] = a;
  }
}

extern "C" void kernel_launch(void* const* d_in, const int* in_sizes, int n_in,
                              void* d_out, int out_size, void* d_ws, size_t ws_size,
                              hipStream_t stream) {
  const float* drug = (const float*)d_in[2];
  const float* rel  = (const float*)d_in[3];
  const float* tail = (const float*)d_in[4];
  const float* W1   = (const float*)d_in[5];
  const float* b1   = (const float*)d_in[6];
  const float* W2   = (const float*)d_in[7];
  const float* b2   = (const float*)d_in[8];
  const float* Wc   = (const float*)d_in[9];
  const float* bc   = (const float*)d_in[10];
  const float* gam  = (const float*)d_in[11];
  const float* bet  = (const float*)d_in[12];
  const int*   dkg  = (const int*)d_in[13];
  float* out = (float*)d_out;
  float* y = out + 640000;                   // Output-1 region doubles as y

  // ---- Workspace (ws_size = 256 MiB per R9 fill counters) ----
  char* w = (char*)d_ws;
  int*   cand = (int*)(w);                   // 3,840,000 B
  int*   degs = (int*)(w + 4000000);         // 163,840 B (zeroed by memset)
  int*   cnt  = (int*)(w + 4200000);         // 40,000 B (zeroed in k_hist)
  float* psq  = (float*)(w + 4300000);       // 512 B (zeroed in k_cand)

  // Threefry key derivation (seed 42, partitionable split semantics)
  u32 k1x, k1y, k2x, k2y, khx, khy, klx, kly;
  tf2x32(0u, 42u, 0u, 0u, k1x, k1y);   // split(key)[0] -> uniform r
  tf2x32(0u, 42u, 0u, 1u, k2x, k2y);   // split(key)[1] -> randint key
  tf2x32(k2x, k2y, 0u, 0u, khx, khy);  // split(k2)[0] -> higher_bits
  tf2x32(k2x, k2y, 0u, 1u, klx, kly);  // split(k2)[1] -> lower_bits

  hipMemsetAsync(degs, 0, 4 * SH * sizeof(int), stream);
  k_hist<<<(NE / 4 + 255) / 256, 256, 0, stream>>>((const int4*)dkg, degs, cnt);
  k_cand<<<(NE / 4 + 255) / 256, 256, 0, stream>>>((const int4*)dkg, degs, cnt,
                                                   cand, psq, k1x, k1y);
  k_ge<<<625, 256, 0, stream>>>(dkg, cand, cnt, degs, drug, rel, tail,
                                W1, b1, W2, b2, Wc, bc, y, psq,
                                k1x, k1y, khx, khy, klx, kly);
  k_final<<<(322500 + 255) / 256, 256, 0, stream>>>((const float4*)d_in[0],
                                                    (const float4*)d_in[1],
                                                    gam, bet, psq,
                                                    (float4*)out);
}